// Round 6
// baseline (636.726 us; speedup 1.0000x reference)
//
#include <hip/hip_runtime.h>
#include <hip/hip_bf16.h>
#include <stdint.h>

// Problem constants (fixed by reference)
#define DIMN    2048
#define HIDDEN  2048
#define NHEADS  4
#define HDIM    512
#define BATCH   4
#define SEQ     2048
#define NTOK    (BATCH*SEQ)      // 8192 tokens
#define G4      (4*HIDDEN)       // 8192 gate width
#define EPSV    1e-6f
#define CHUNK   128
#define NCHUNK  (SEQ/CHUNK)      // 16

typedef short short8 __attribute__((ext_vector_type(8)));
typedef float floatx4 __attribute__((ext_vector_type(4)));

union BV8 { uint4 u; __hip_bfloat16 h[8]; unsigned short s[8]; };

__device__ __forceinline__ float fast_sigmoid(float x) {
    return 1.0f / (1.0f + __expf(-x));
}
__device__ __forceinline__ float fast_tanh(float x) {
    return 1.0f - 2.0f / (__expf(2.0f * x) + 1.0f);
}
__device__ __forceinline__ float b2f(unsigned short u) {
    union { unsigned int ui; float f; } v; v.ui = ((unsigned int)u) << 16; return v.f;
}

// async global->LDS, 16B per lane; LDS dest = wave-uniform base + lane*16
__device__ __forceinline__ void gld_lds16(const void* gp, void* lp) {
    __builtin_amdgcn_global_load_lds(
        (const __attribute__((address_space(1))) void*)gp,
        (__attribute__((address_space(3))) void*)lp, 16, 0, 0);
}

// ---------------------------------------------------------------------------
// f32 -> bf16 cast, 8 elems/thread
// ---------------------------------------------------------------------------
__global__ __launch_bounds__(256) void cast_f32_bf16(
    const float* __restrict__ in, __hip_bfloat16* __restrict__ out, int n8)
{
    int i = blockIdx.x * 256 + threadIdx.x;
    if (i >= n8) return;
    const float4* p = (const float4*)(in + (size_t)i * 8);
    float4 a = p[0], b = p[1];
    BV8 v;
    v.h[0] = __float2bfloat16(a.x); v.h[1] = __float2bfloat16(a.y);
    v.h[2] = __float2bfloat16(a.z); v.h[3] = __float2bfloat16(a.w);
    v.h[4] = __float2bfloat16(b.x); v.h[5] = __float2bfloat16(b.y);
    v.h[6] = __float2bfloat16(b.z); v.h[7] = __float2bfloat16(b.w);
    *(uint4*)(out + (size_t)i * 8) = v.u;
}

// ---------------------------------------------------------------------------
// GEMM: C[M][N] = A[M][K] @ Bt[N][K]^T   (bf16 in, fp32 acc)
// 256x256 tile, BK=64, 512 threads = 8 waves (2M x 4N), each wave 128x64.
// ROUND-4 SCHEDULE, UNCHANGED (measured best: GEMM2 315us, MfmaUtil 39%,
// 0 bank conflicts; r0-r4 variants all 315-335us -> structure plateau).
// 4 phases/K-tile, ONE raw s_barrier per phase, NO manual lgkm waits:
//   { ds_reads; stage 1 chunk; setprio(1); 16 MFMA; setprio(0); s_barrier }
// Backend emits counted lgkmcnt(N) inside the MFMA cluster.
// Safety: every ds_read in a phase is consumed by an in-phase MFMA, so all
// of a wave's reads complete before its phase-end barrier. Region ledger:
//   ph0 stage A(t+1,q1): region last read as av' in (t-1)ph2.
//   ph1 stage A(t+2,q0): region last read as av  in t ph0.
//   ph2 stage B(t+2,q0): region last read as b0  in t ph0.
//   ph3 stage B(t+2,q1): region last read as b1  in t ph1.
// Visibility: vmcnt(6) at t ph3-end leaves only the newest 3 chunks
// outstanding -> tile t+1 fully resident. vmcnt(0) once at t==NT-2.
// Swizzle: source-chunk XOR (LDS[row][c]=G[row][c^(row&7)], 16B granules),
// measured SQ_LDS_BANK_CONFLICT == 0 with the matching read-side XOR.
// EPILOGUE: 0 = bf16 store; 1 = bias+gate activations -> bf16; 2 = f32 store
// ASRC: 0 = contiguous rows; 1 = head-gather (row,k) -> Ag[row*lda +
//       (k>>9)*2048 + (k&511)]  (BK=64 chunk never crosses a 512 block)
// ---------------------------------------------------------------------------
template <int EPILOGUE, int ASRC>
__global__ __launch_bounds__(512, 2) void gemm256(
    const __hip_bfloat16* __restrict__ A,
    const __hip_bfloat16* __restrict__ Bt,
    void* __restrict__ Cout,
    const float* __restrict__ bias,
    int M, int N, int K, int lda)
{
    __shared__ __align__(16) short sA[2][256 * 64];   // 64 KiB
    __shared__ __align__(16) short sB[2][256 * 64];   // 64 KiB

    const int tid  = threadIdx.x;
    const int wave = tid >> 6, lane = tid & 63;
    const int wm = wave >> 2, wn = wave & 3;          // 2 x 4 wave grid
    const int quad = lane >> 4, lr = lane & 15;
    const int r8  = lane >> 3;                        // row within 8-row slab
    const int gcs = ((lane & 7) ^ r8) * 8;            // swizzled src chunk (shorts)
    const int rl7 = lr & 7;

    // bijective XCD swizzle (all launch shapes have nwg % 8 == 0)
    const int gx   = gridDim.x;
    const int nwg  = gx * gridDim.y;
    const int orig = blockIdx.y * gx + blockIdx.x;
    const int wg   = (orig & 7) * (nwg >> 3) + (orig >> 3);
    const int bm = wg / gx, bn = wg % gx;

    const short* Ag = (const short*)A + (size_t)(bm * 256) * lda;
    const short* Bg = (const short*)Bt + (size_t)(bn * 256) * K;

    floatx4 acc[8][4];
#pragma unroll
    for (int i = 0; i < 8; ++i)
#pragma unroll
        for (int j = 0; j < 4; ++j) acc[i][j] = (floatx4)0.0f;

    const int NT = K >> 6;

    auto stageA = [&](int kt, int qm) {
        const int kb = kt << 6;
        size_t acol;
        if (ASRC == 0) acol = (size_t)(kb + gcs);
        else           acol = (size_t)(((kb >> 9) << 11) + (kb & 511) + gcs);
        short* dst = &sA[kt & 1][0];
#pragma unroll
        for (int e = 0; e < 2; ++e) {
            const int base = qm * 128 + e * 64 + wave * 8;   // wave-uniform
            const int row  = base + r8;
            const int grow = ((row >> 6) & 1) * 128 + qm * 64 + (row & 63);
            gld_lds16(Ag + (size_t)grow * lda + acol, dst + base * 64);
        }
    };
    auto stageB = [&](int kt, int qn) {
        const int kb = kt << 6;
        short* dst = &sB[kt & 1][0];
#pragma unroll
        for (int e = 0; e < 2; ++e) {
            const int base = qn * 128 + e * 64 + wave * 8;   // wave-uniform
            const int row  = base + r8;
            const int grow = ((row >> 5) & 3) * 64 + qn * 32 + (row & 31);
            gld_lds16(Bg + (size_t)grow * K + kb + gcs, dst + base * 64);
        }
    };

    // prologue: tile0 c0..c3, tile1 {A-q0, B-q0, B-q1} (7 chunks, 14 loads);
    // vmcnt(6) -> tile0 fully resident (newest 3 chunks may be in flight).
    stageA(0, 0); stageB(0, 0); stageB(0, 1); stageA(0, 1);
    stageA(1, 0); stageB(1, 0); stageB(1, 1);
    asm volatile("s_waitcnt vmcnt(6)" ::: "memory");
    __builtin_amdgcn_s_barrier();

    short8 av[4][2], b0[2][2], b1[2][2];

    for (int t = 0; t < NT; ++t) {
        const short* lA = &sA[t & 1][0];
        const short* lB = &sB[t & 1][0];

        // ---- phase 0: read A-q0 (8) + B-q0 (4); stage A(t+1,q1); MFMA Q00
#pragma unroll
        for (int kc = 0; kc < 2; ++kc) {
            const int co = (((kc * 4 + quad) ^ rl7) << 3);
#pragma unroll
            for (int m = 0; m < 4; ++m)
                av[m][kc] = *(const short8*)&lA[(wm * 64 + m * 16 + lr) * 64 + co];
#pragma unroll
            for (int j = 0; j < 2; ++j)
                b0[j][kc] = *(const short8*)&lB[(wn * 32 + j * 16 + lr) * 64 + co];
        }
        if (t + 1 < NT) stageA(t + 1, 1);
        __builtin_amdgcn_s_setprio(1);
#pragma unroll
        for (int m = 0; m < 4; ++m)
#pragma unroll
            for (int j = 0; j < 2; ++j)
#pragma unroll
                for (int kc = 0; kc < 2; ++kc)
                    acc[m][j] = __builtin_amdgcn_mfma_f32_16x16x32_bf16(
                        av[m][kc], b0[j][kc], acc[m][j], 0, 0, 0);
        __builtin_amdgcn_s_setprio(0);
        __builtin_amdgcn_s_barrier();

        // ---- phase 1: read B-q1 (4); stage A(t+2,q0); MFMA Q01
#pragma unroll
        for (int kc = 0; kc < 2; ++kc) {
            const int co = (((kc * 4 + quad) ^ rl7) << 3);
#pragma unroll
            for (int j = 0; j < 2; ++j)
                b1[j][kc] = *(const short8*)&lB[(128 + wn * 32 + j * 16 + lr) * 64 + co];
        }
        if (t + 2 < NT) stageA(t + 2, 0);
        __builtin_amdgcn_s_setprio(1);
#pragma unroll
        for (int m = 0; m < 4; ++m)
#pragma unroll
            for (int j = 0; j < 2; ++j)
#pragma unroll
                for (int kc = 0; kc < 2; ++kc)
                    acc[m][2 + j] = __builtin_amdgcn_mfma_f32_16x16x32_bf16(
                        av[m][kc], b1[j][kc], acc[m][2 + j], 0, 0, 0);
        __builtin_amdgcn_s_setprio(0);
        __builtin_amdgcn_s_barrier();

        // ---- phase 2: read A-q1 (8, overwrite av); stage B(t+2,q0); MFMA Q11
#pragma unroll
        for (int kc = 0; kc < 2; ++kc) {
            const int co = (((kc * 4 + quad) ^ rl7) << 3);
#pragma unroll
            for (int m = 0; m < 4; ++m)
                av[m][kc] = *(const short8*)&lA[(128 + wm * 64 + m * 16 + lr) * 64 + co];
        }
        if (t + 2 < NT) stageB(t + 2, 0);
        __builtin_amdgcn_s_setprio(1);
#pragma unroll
        for (int m = 0; m < 4; ++m)
#pragma unroll
            for (int j = 0; j < 2; ++j)
#pragma unroll
                for (int kc = 0; kc < 2; ++kc)
                    acc[4 + m][2 + j] = __builtin_amdgcn_mfma_f32_16x16x32_bf16(
                        av[m][kc], b1[j][kc], acc[4 + m][2 + j], 0, 0, 0);
        __builtin_amdgcn_s_setprio(0);
        __builtin_amdgcn_s_barrier();

        // ---- phase 3: regs only; stage B(t+2,q1); MFMA Q10; counted vmcnt
        if (t + 2 < NT) stageB(t + 2, 1);
        __builtin_amdgcn_s_setprio(1);
#pragma unroll
        for (int m = 0; m < 4; ++m)
#pragma unroll
            for (int j = 0; j < 2; ++j)
#pragma unroll
                for (int kc = 0; kc < 2; ++kc)
                    acc[4 + m][j] = __builtin_amdgcn_mfma_f32_16x16x32_bf16(
                        av[m][kc], b0[j][kc], acc[4 + m][j], 0, 0, 0);
        __builtin_amdgcn_s_setprio(0);
        if (t < NT - 2)       asm volatile("s_waitcnt vmcnt(6)" ::: "memory");
        else if (t == NT - 2) asm volatile("s_waitcnt vmcnt(0)" ::: "memory");
        __builtin_amdgcn_s_barrier();
    }

    // epilogue: row = bm*256 + wm*128 + mt*16 + quad*4 + r
    //           col = bn*256 + wn*64  + nt*16 + lr
    const int colbase = bn * 256 + wn * 64;
    const int rowbase = bm * 256 + wm * 128;

    if (EPILOGUE == 0) {
        __hip_bfloat16* O = (__hip_bfloat16*)Cout;
#pragma unroll
        for (int mt = 0; mt < 8; ++mt)
#pragma unroll
            for (int nt = 0; nt < 4; ++nt)
#pragma unroll
                for (int r = 0; r < 4; ++r) {
                    int row = rowbase + mt * 16 + quad * 4 + r;
                    int col = colbase + nt * 16 + lr;
                    O[(size_t)row * N + col] = __float2bfloat16(acc[mt][nt][r]);
                }
    } else if (EPILOGUE == 1) {
        __hip_bfloat16* O = (__hip_bfloat16*)Cout;
#pragma unroll
        for (int nt = 0; nt < 4; ++nt) {
            int col = colbase + nt * 16 + lr;
            int g = (col >> 9) & 3;   // uniform within a 16-col MFMA tile
            float bv = bias[col];
#pragma unroll
            for (int mt = 0; mt < 8; ++mt)
#pragma unroll
                for (int r = 0; r < 4; ++r) {
                    int row = rowbase + mt * 16 + quad * 4 + r;
                    float v = acc[mt][nt][r] + bv;
                    if (g == 0)       v = __expf(v);
                    else if (g == 3)  v = fast_tanh(v);
                    else              v = fast_sigmoid(v);
                    O[(size_t)row * N + col] = __float2bfloat16(v);
                }
        }
    } else {
        float* O = (float*)Cout;
#pragma unroll
        for (int mt = 0; mt < 8; ++mt)
#pragma unroll
            for (int nt = 0; nt < 4; ++nt)
#pragma unroll
                for (int r = 0; r < 4; ++r) {
                    int row = rowbase + mt * 16 + quad * 4 + r;
                    int col = colbase + nt * 16 + lr;
                    O[(size_t)row * N + col] = acc[mt][nt][r];
                }
    }
}

// ---------------------------------------------------------------------------
// Chunk-decomposed linear scan. c_t = f_t*c_{t-1} + i_t*cd_t is linear in c,
// so split SEQ into 16 chunks of 128:
//   pass1: per (dim, chunk) scan from c=0 in f32, keep P = prod(f) in f32;
//          store only chunk summaries cLast/PLast (f32, 1 MB).
//   pass2 (FUSED with norm): per (head, chunk) block of 512 threads.
//     Scan phase: thread d scans its dim over the 128-step chunk (identical
//     math/rounding to the old pass2), writing c (bf16) to LDS[t][d] instead
//     of HBM cbuf -- saves the 32MB cbuf write + 32MB norm re-read.
//     Norm phase (after one __syncthreads): wave w handles timesteps
//     w*16..w*16+15; per t: 64 lanes x 8 dims from LDS, shfl-reduce rms,
//     h = o * tanh(c_norm) written into the gates i-slot (same addresses,
//     same rounding as the old norm_kernel).
// ---------------------------------------------------------------------------
struct G16 { unsigned short i[16], f[16], c[16]; };

__device__ __forceinline__ void load_g16(const unsigned short* __restrict__ g,
                                         int t0, G16& o)
{
#pragma unroll
    for (int j = 0; j < 16; ++j) {
        const unsigned short* gp = g + (size_t)(t0 + j) * G4;
        o.i[j] = gp[0]; o.f[j] = gp[512]; o.c[j] = gp[1536];
    }
}
__device__ __forceinline__ void comp_sum16(const G16& gg, float& c, float& P)
{
#pragma unroll
    for (int j = 0; j < 16; ++j) {
        float iv = b2f(gg.i[j]);
        float fv = b2f(gg.f[j]);
        float cd = b2f(gg.c[j]);
        c = fmaf(fv, c, iv * cd);
        P *= fv;
    }
}
__device__ __forceinline__ float comp_lds16(const G16& gg, float c,
                                            __hip_bfloat16* __restrict__ sc,
                                            int t0, int d)
{
#pragma unroll
    for (int j = 0; j < 16; ++j) {
        float iv = b2f(gg.i[j]);
        float fv = b2f(gg.f[j]);
        float cd = b2f(gg.c[j]);
        c = fmaf(fv, c, iv * cd);
        sc[(t0 + j) * HDIM + d] = __float2bfloat16(c);
    }
    return c;
}

__global__ __launch_bounds__(256) void scan_pass1(
    const __hip_bfloat16* __restrict__ gates,
    float* __restrict__ cLast, float* __restrict__ PLast)
{
    int blk = blockIdx.x;              // 0..511
    int dh = blk & 1;
    int j  = (blk >> 1) & 15;
    int bh = blk >> 5;                 // 0..15
    int b = bh >> 2, h = bh & 3;
    int d = dh * 256 + threadIdx.x;    // 0..511
    int bhd = bh * 512 + d;

    const unsigned short* g = (const unsigned short*)gates
        + (size_t)(b * SEQ + j * CHUNK) * G4 + h * 2048 + d;

    float c = 0.0f, P = 1.0f;
    G16 A, B;
    load_g16(g, 0, A);
    for (int t0 = 0; t0 < CHUNK; t0 += 32) {
        load_g16(g, t0 + 16, B);
        comp_sum16(A, c, P);
        if (t0 + 32 < CHUNK) load_g16(g, t0 + 32, A);
        comp_sum16(B, c, P);
    }
    cLast[j * 8192 + bhd] = c;
    PLast[j * 8192 + bhd] = P;
}

__global__ __launch_bounds__(512) void scan_pass2_norm(
    const __hip_bfloat16* __restrict__ gates_c,    // const view for scan
    const float* __restrict__ cLast, const float* __restrict__ PLast,
    __hip_bfloat16* __restrict__ gates,            // mutable: h into i-slot
    const float* __restrict__ rms_w)
{
    __shared__ __hip_bfloat16 sc[CHUNK * HDIM];    // 128 x 512 bf16 = 128 KiB

    int blk = blockIdx.x;              // 0..255
    int j  = blk & 15;
    int bh = blk >> 4;                 // 0..15
    int b = bh >> 2, h = bh & 3;
    int d = threadIdx.x;               // 0..511
    int bhd = bh * 512 + d;

    // ---- scan phase (identical math to old pass2; c -> LDS) ----
    float c = 0.0f;
    for (int k = 0; k < j; ++k)
        c = fmaf(PLast[k * 8192 + bhd], c, cLast[k * 8192 + bhd]);

    const unsigned short* g = (const unsigned short*)gates_c
        + (size_t)(b * SEQ + j * CHUNK) * G4 + h * 2048 + d;

    G16 A, B;
    load_g16(g, 0, A);
    for (int t0 = 0; t0 < CHUNK; t0 += 32) {
        load_g16(g, t0 + 16, B);
        c = comp_lds16(A, c, sc, t0, d);
        if (t0 + 32 < CHUNK) load_g16(g, t0 + 32, A);
        c = comp_lds16(B, c, sc, t0 + 16, d);
    }
    __syncthreads();

    // ---- norm phase: wave w -> timesteps w*16 .. w*16+15 ----
    const int wave = threadIdx.x >> 6, lane = threadIdx.x & 63;

    float4 w0 = *(const float4*)&rms_w[lane * 8];
    float4 w1 = *(const float4*)&rms_w[lane * 8 + 4];
    float w[8] = { w0.x, w0.y, w0.z, w0.w, w1.x, w1.y, w1.z, w1.w };

    for (int it = 0; it < 16; ++it) {
        int t = wave * 16 + it;
        size_t tok = (size_t)(b * SEQ + j * CHUNK + t);

        BV8 cv; cv.u = *(const uint4*)&sc[t * HDIM + lane * 8];
        float cf[8]; float s = 0.0f;
#pragma unroll
        for (int q = 0; q < 8; ++q) { cf[q] = b2f(cv.s[q]); s += cf[q] * cf[q]; }
#pragma unroll
        for (int off = 32; off > 0; off >>= 1) s += __shfl_xor(s, off, 64);
        float rs = rsqrtf(s * (1.0f / 512.0f) + EPSV);

        BV8 ov; ov.u = *(const uint4*)(gates + tok * G4 + h * 2048 + 1024 + lane * 8);
        BV8 hv;
#pragma unroll
        for (int q = 0; q < 8; ++q) {
            float o = b2f(ov.s[q]);
            hv.h[q] = __float2bfloat16(o * fast_tanh(cf[q] * rs * w[q]));
        }
        *(uint4*)(gates + tok * G4 + h * 2048 + lane * 8) = hv.u;
    }
}

// ---------------------------------------------------------------------------
// Workspace plan (192 MiB total, lifetime-aliased):
//  [0,  32MiB)  wgb (bf16 W_gate)   ... after GEMM2: [0,8M)=wob,
//                                       [8M,8.5M)=cLast, [8.5M,9M)=PLast
//  [32, 64MiB)  xpb (bf16 GEMM1 out)... dead after GEMM2 (c stays in LDS now)
//  [64,192MiB)  gates (bf16)        ... before GEMM2: wib + xb
// ---------------------------------------------------------------------------
extern "C" void kernel_launch(void* const* d_in, const int* in_sizes, int n_in,
                              void* d_out, int out_size, void* d_ws, size_t ws_size,
                              hipStream_t stream)
{
    const float* x      = (const float*)d_in[0];   // (4,2048,2048)
    const float* W_in   = (const float*)d_in[1];   // (2048,2048)
    const float* W_gate = (const float*)d_in[2];   // (8192,2048)
    const float* b_gate = (const float*)d_in[3];   // (8192,)
    const float* rms_w  = (const float*)d_in[4];   // (512,)
    const float* W_out  = (const float*)d_in[5];   // (2048,2048)
    float* out = (float*)d_out;                    // (4,2048,2048)

    char* base = (char*)d_ws;
    __hip_bfloat16* wgb   = (__hip_bfloat16*)base;                             // 32 MiB
    __hip_bfloat16* xpb   = (__hip_bfloat16*)(base + (((size_t)32) << 20));    // 32 MiB
    __hip_bfloat16* gates = (__hip_bfloat16*)(base + (((size_t)64) << 20));    // 128 MiB
    // aliases (lifetime-disjoint, stream-ordered):
    __hip_bfloat16* wib  = gates;                                              // 8 MiB
    __hip_bfloat16* xb   = (__hip_bfloat16*)(base + (((size_t)72) << 20));     // 32 MiB
    __hip_bfloat16* wob  = wgb;                                                // 8 MiB
    float* cLast = (float*)(base + (((size_t)8) << 20));                       // 512 KiB
    float* PLast = (float*)(base + (((size_t)8) << 20) + (512 << 10));         // 512 KiB

    // 1) casts to bf16 (wib/xb live in gates region; gates not written yet)
    cast_f32_bf16<<<(HIDDEN * DIMN) / 8 / 256, 256, 0, stream>>>(W_in, wib, (HIDDEN * DIMN) / 8);
    cast_f32_bf16<<<(NTOK * DIMN) / 8 / 256, 256, 0, stream>>>(x, xb, (NTOK * DIMN) / 8);
    cast_f32_bf16<<<(G4 * HIDDEN) / 8 / 256, 256, 0, stream>>>(W_gate, wgb, (G4 * HIDDEN) / 8);

    // 2) xp = x @ W_in^T  -> bf16
    {
        dim3 grid(HIDDEN / 256, NTOK / 256);   // 8 x 32 = 256 wgs
        gemm256<0, 0><<<grid, 512, 0, stream>>>(xb, wib, xpb, nullptr,
                                                NTOK, HIDDEN, DIMN, DIMN);
    }
    // 3) gates = act(xp @ W_gate^T + b) -> bf16 (overwrites wib/xb: dead now)
    {
        dim3 grid(G4 / 256, NTOK / 256);       // 32 x 32 = 1024 wgs
        gemm256<1, 0><<<grid, 512, 0, stream>>>(xpb, wgb, gates, b_gate,
                                                NTOK, G4, HIDDEN, HIDDEN);
    }
    // 4) cast W_out -> wob (overwrites wgb: dead now)
    cast_f32_bf16<<<(DIMN * HIDDEN) / 8 / 256, 256, 0, stream>>>(W_out, wob, (DIMN * HIDDEN) / 8);

    // 5) chunk-decomposed scan; pass2 fused with RMS-norm + output gate
    //    (h written into the gates i-slot; c never touches HBM)
    scan_pass1<<<BATCH * NHEADS * NCHUNK * 2, 256, 0, stream>>>(gates, cLast, PLast);
    scan_pass2_norm<<<BATCH * NHEADS * NCHUNK, 512, 0, stream>>>(gates, cLast, PLast,
                                                                 gates, rms_w);

    // 6) out = h @ W_out^T -> f32 (A head-gathered from gates i-slot)
    {
        dim3 grid(DIMN / 256, NTOK / 256);     // 8 x 32 = 256 wgs
        gemm256<2, 1><<<grid, 512, 0, stream>>>(gates, wob, out, nullptr,
                                                NTOK, DIMN, HIDDEN, G4);
    }
}